// Round 3
// baseline (206.953 us; speedup 1.0000x reference)
//
#include <hip/hip_runtime.h>

// KPConv pipeline v5:
//   k_prep (merged): blocks [0,1563): x [50000,64] f32 -> xb bf16
//                    blocks [1563,1578): Wt transpose via LDS, full-line writes
//                    (old kpconv_wt did 123K scattered 2B stores -> cross-XCD
//                     partial-line RMW thrash; now each block owns complete
//                     128B lines of Wt and writes coalesced uint4)
//   k_fused: 512 thr = 8 waves, 16 points, grid 3125, 39KB LDS -> 4 blk/CU
//     Phase A: 2 points per wave sequentially (each point = v2-agg structure:
//              32 parallel u16 gathers + 4 MFMA), wf -> LDS (swizzled).
//     Phase B: 8 waves = 8 col-groups, full K (30 MFMA steps), no reduce.
//   wf never touches HBM.

#define NPTS   50000
#define HNB    32
#define KPTS   15
#define CING   64
#define COUTG  128
#define KDIM   960
#define MSUP   50000
#define INV_EXT 13.888889f

#define PPB       16    // points per block (= MFMA M)
#define WF_PITCH  968   // u16 per point-row (1936B)

#define X2BF_BLKS 1563  // ceil(50000*64/8/256)
#define WT_BLKS   15    // 960/64
#define TWP       72    // u16 pitch in wt transpose tile (144B, 16B-aligned)

typedef __attribute__((ext_vector_type(8))) short bf16x8;
typedef __attribute__((ext_vector_type(8))) unsigned short u16x8;
typedef __attribute__((ext_vector_type(4))) float f32x4;

static __device__ __forceinline__ unsigned short f2bf(float f) {
    unsigned int u = __float_as_uint(f);
    u += 0x7FFFu + ((u >> 16) & 1u);
    return (unsigned short)(u >> 16);
}

// ---------------- k_prep: x->bf16 + weight transpose ----------------
__global__ __launch_bounds__(256) void kpconv_prep(const float* __restrict__ x,
                                                   unsigned short* __restrict__ xb,
                                                   const float* __restrict__ wgt,
                                                   unsigned short* __restrict__ Wt) {
    __shared__ unsigned short tw[128 * TWP];   // 18432 B (only used by wt blocks)
    const int tid = threadIdx.x;
    if (blockIdx.x < X2BF_BLKS) {
        int i = (blockIdx.x * 256 + tid) * 8;
        if (i >= MSUP * CING) return;
        float4 a = *(const float4*)(x + i);
        float4 b = *(const float4*)(x + i + 4);
        u16x8 o;
        o[0] = f2bf(a.x); o[1] = f2bf(a.y); o[2] = f2bf(a.z); o[3] = f2bf(a.w);
        o[4] = f2bf(b.x); o[5] = f2bf(b.y); o[6] = f2bf(b.z); o[7] = f2bf(b.w);
        *(u16x8*)(xb + i) = o;
        return;
    }
    // weight transpose: this block owns kc chunk [kc0, kc0+64) for all 128 o.
    // wgt[kc][o] (kc = k*64+c) -> Wt[o][kc]; each output row-chunk = one full
    // aligned 128B line (o*1920 + kc0*2, 1920 = 15*128).
    const int kc0 = (blockIdx.x - X2BF_BLKS) * 64;
#pragma unroll
    for (int it = 0; it < 32; ++it) {
        int idx = it * 256 + tid;          // 0..8191 = kcl*128 + o
        int kcl = idx >> 7, o = idx & 127;
        tw[o * TWP + kcl] = f2bf(wgt[(size_t)(kc0 + kcl) * COUTG + o]);
    }
    __syncthreads();
#pragma unroll
    for (int it = 0; it < 4; ++it) {
        int idx = it * 256 + tid;          // 0..1023 = o*8 + c16
        int o = idx >> 3, c16 = idx & 7;
        uint4 v = *(const uint4*)&tw[o * TWP + c16 * 8];
        *(uint4*)&Wt[(size_t)o * KDIM + kc0 + c16 * 8] = v;
    }
}

// ---------------- k_fused: aggregate + GEMM ----------------
// Phase A MFMA (swapped operands):
//   A-frag = gathered x: lane (l15,quad), elem j -> x[nb(h=quad*8+j)][nt*16+l15]
//   B-frag = w:          lane l15 = k,    elem j -> w(h=quad*8+j, k)
//   D[m=quad*4+r][n=l15] = wf[k=l15][c = nt*16 + quad*4 + r]
// LDS wf element kd=k*64+c at row-byte (kd*2) ^ (((kd>>5)&7)<<4).
// Phase B: A-frag row = point = l15, kd0 = s*32 + quad*8; key (s&7)<<4 uniform
//   per instr; 8 lanes per 16B slot (balanced) -> conflict-free b128.
__global__ __launch_bounds__(512, 8) void kpconv_fused(
    const float* __restrict__ q_pts, const float* __restrict__ s_pts,
    const int* __restrict__ inds, const unsigned short* __restrict__ xb,
    const float* __restrict__ kpts, const unsigned short* __restrict__ Wt,
    const float* __restrict__ bias, float* __restrict__ out)
{
    __shared__ float4 nb[PPB * HNB];                 // 8192 B
    __shared__ unsigned short wfs[PPB * WF_PITCH];   // 30976 B (39.2 KB -> 4 blk/CU)

    const int tid  = threadIdx.x;
    const int wav  = tid >> 6;        // 0..7
    const int lane = tid & 63;
    const int l15  = lane & 15;
    const int quad = lane >> 4;
    const int p0   = blockIdx.x * PPB;

    // ---- stage all 16 points' neighbor displacements: 1 thread per (p,h) ----
    {
        const int p = tid >> 5, h = tid & 31;
        const int n = p0 + p;
        int m = inds[n * HNB + h];
        float qx = q_pts[n * 3 + 0];
        float qy = q_pts[n * 3 + 1];
        float qz = q_pts[n * 3 + 2];
        nb[p * HNB + h] = make_float4(s_pts[m * 3 + 0] - qx,
                                      s_pts[m * 3 + 1] - qy,
                                      s_pts[m * 3 + 2] - qz,
                                      __int_as_float(m));
    }
    __syncthreads();

    // ---- Phase A: 2 points per wave ----
    const bool kvalid = (l15 < KPTS);
    const int  kidx   = kvalid ? l15 : 0;
    const float kx = kpts[kidx * 3 + 0];
    const float ky = kpts[kidx * 3 + 1];
    const float kz = kpts[kidx * 3 + 2];

    for (int pp = 0; pp < 2; ++pp) {
        const int p = wav * 2 + pp;
        bf16x8 af;
        int mrow[8];
#pragma unroll
        for (int j = 0; j < 8; ++j) {
            float4 v = nb[p * HNB + quad * 8 + j];
            mrow[j] = __float_as_int(v.w);
            float dx = v.x - kx, dy = v.y - ky, dz = v.z - kz;
            float d  = sqrtf(dx * dx + dy * dy + dz * dz);
            float w  = kvalid ? fmaxf(0.f, 1.f - d * INV_EXT) : 0.f;
            af[j] = (short)f2bf(w);
        }

        f32x4 acc[4];
#pragma unroll
        for (int nt = 0; nt < 4; ++nt) acc[nt] = (f32x4){0.f, 0.f, 0.f, 0.f};

#pragma unroll
        for (int nt = 0; nt < 4; ++nt) {
            bf16x8 bfr;
#pragma unroll
            for (int j = 0; j < 8; ++j)
                bfr[j] = (short)xb[(((size_t)mrow[j]) << 6) + nt * 16 + l15];
            acc[nt] = __builtin_amdgcn_mfma_f32_16x16x32_bf16(bfr, af, acc[nt], 0, 0, 0);
        }

        if (kvalid) {   // lane's k = l15; k==15 unused (KDIM = 15*64)
            char* rowp = (char*)wfs + p * (WF_PITCH * 2);
#pragma unroll
            for (int nt = 0; nt < 4; ++nt) {
                unsigned int lo = (unsigned)f2bf(acc[nt][0]) | ((unsigned)f2bf(acc[nt][1]) << 16);
                unsigned int hi = (unsigned)f2bf(acc[nt][2]) | ((unsigned)f2bf(acc[nt][3]) << 16);
                // kd = l15*64 + nt*16 + quad*4 + r ; key = ((kd>>5)&7)
                const int off = (l15 * 128 + nt * 32 + quad * 8) ^ ((((l15 << 1) + (nt >> 1)) & 7) << 4);
                *(uint2*)(rowp + off) = make_uint2(lo, hi);
            }
        }
    }
    __syncthreads();

    // ---- Phase B: wave = col-group, full K (30 steps) ----
    f32x4 oacc = (f32x4){0.f, 0.f, 0.f, 0.f};
    const unsigned short* b0 = Wt + (size_t)(wav * 16 + l15) * KDIM + quad * 8;

#pragma unroll
    for (int s = 0; s < 30; ++s) {
        const int aoff = (s * 64 + quad * 16) ^ ((s & 7) << 4);
        bf16x8 afr = *(const bf16x8*)((const char*)wfs + l15 * (WF_PITCH * 2) + aoff);
        bf16x8 wfr = *(const bf16x8*)(b0 + s * 32);
        oacc = __builtin_amdgcn_mfma_f32_16x16x32_bf16(afr, wfr, oacc, 0, 0, 0);
    }

    // ---- bias + write out ----
    {
        const int col = wav * 16 + l15;
        const float bv = bias[col];
#pragma unroll
        for (int r = 0; r < 4; ++r) {
            const int row = p0 + quad * 4 + r;        // exact: 3125*16 = 50000
            out[(size_t)row * COUTG + col] = oacc[r] + bv;
        }
    }
}

extern "C" void kernel_launch(void* const* d_in, const int* in_sizes, int n_in,
                              void* d_out, int out_size, void* d_ws, size_t ws_size,
                              hipStream_t stream) {
    const float* q_pts = (const float*)d_in[0];
    const float* s_pts = (const float*)d_in[1];
    const int*   inds  = (const int*)d_in[2];
    const float* x     = (const float*)d_in[3];
    const float* kpts  = (const float*)d_in[4];
    const float* wgt   = (const float*)d_in[5];
    const float* bias  = (const float*)d_in[6];
    float* out = (float*)d_out;

    // ws layout: xb [50000*64] bf16 | Wt [128*960] bf16
    unsigned short* xb = (unsigned short*)d_ws;
    unsigned short* Wt = xb + (size_t)MSUP * CING;

    kpconv_prep<<<X2BF_BLKS + WT_BLKS, 256, 0, stream>>>(x, xb, wgt, Wt);
    kpconv_fused<<<NPTS / PPB, 512, 0, stream>>>(q_pts, s_pts, inds, xb, kpts, Wt, bias, out);
}

// Round 4
// 201.214 us; speedup vs baseline: 1.0285x; 1.0285x over previous
//
#include <hip/hip_runtime.h>

// KPConv pipeline v6 — fused aggregate+GEMM, latency-repaired:
//   k_prep: x -> xb bf16  +  Wt transpose (full-line writes).
//   k_fused: 512 thr = 8 waves, 16 points, grid 3125.
//     Phase A: 2 points/wave; per point ALL 32 gather loads issued before
//              any MFMA (needs >64 VGPR: launch_bounds(512,4) -> 128 cap;
//              v4/v5's (.,8) forced 32 VGPR -> serialized chains, the 131us).
//     wf LDS layout [k][p][c], 128B rows, XOR key ((row>>4)^row)&7:
//              store ~4-way worst, read 2-way (free).
//     Phase B: 8 waves x 16 cols, 30 MFMA steps, Wt from L2.
//     Epilogue: stage out-tile in LDS (reuse nb buffer) -> full-line
//              coalesced global writes (v5 wrote 62.5MB for a 25.6MB out).

#define NPTS   50000
#define HNB    32
#define KPTS   15
#define CING   64
#define COUTG  128
#define KDIM   960
#define MSUP   50000
#define INV_EXT 13.888889f

#define PPB       16    // points per block (= MFMA M)

#define X2BF_BLKS 1563  // ceil(50000*64/8/256)
#define WT_BLKS   15    // 960/64
#define TWP       72    // u16 pitch in wt transpose tile

typedef __attribute__((ext_vector_type(8))) short bf16x8;
typedef __attribute__((ext_vector_type(8))) unsigned short u16x8;
typedef __attribute__((ext_vector_type(4))) float f32x4;

static __device__ __forceinline__ unsigned short f2bf(float f) {
    unsigned int u = __float_as_uint(f);
    u += 0x7FFFu + ((u >> 16) & 1u);
    return (unsigned short)(u >> 16);
}

// ---------------- k_prep: x->bf16 + weight transpose ----------------
__global__ __launch_bounds__(256) void kpconv_prep(const float* __restrict__ x,
                                                   unsigned short* __restrict__ xb,
                                                   const float* __restrict__ wgt,
                                                   unsigned short* __restrict__ Wt) {
    __shared__ unsigned short tw[128 * TWP];
    const int tid = threadIdx.x;
    if (blockIdx.x < X2BF_BLKS) {
        int i = (blockIdx.x * 256 + tid) * 8;
        if (i >= MSUP * CING) return;
        float4 a = *(const float4*)(x + i);
        float4 b = *(const float4*)(x + i + 4);
        u16x8 o;
        o[0] = f2bf(a.x); o[1] = f2bf(a.y); o[2] = f2bf(a.z); o[3] = f2bf(a.w);
        o[4] = f2bf(b.x); o[5] = f2bf(b.y); o[6] = f2bf(b.z); o[7] = f2bf(b.w);
        *(u16x8*)(xb + i) = o;
        return;
    }
    const int kc0 = (blockIdx.x - X2BF_BLKS) * 64;
#pragma unroll
    for (int it = 0; it < 32; ++it) {
        int idx = it * 256 + tid;          // kcl*128 + o
        int kcl = idx >> 7, o = idx & 127;
        tw[o * TWP + kcl] = f2bf(wgt[(size_t)(kc0 + kcl) * COUTG + o]);
    }
    __syncthreads();
#pragma unroll
    for (int it = 0; it < 4; ++it) {
        int idx = it * 256 + tid;          // o*8 + c16
        int o = idx >> 3, c16 = idx & 7;
        uint4 v = *(const uint4*)&tw[o * TWP + c16 * 8];
        *(uint4*)&Wt[(size_t)o * KDIM + kc0 + c16 * 8] = v;
    }
}

// ---------------- k_fused: aggregate + GEMM ----------------
// Phase A MFMA (swapped operands): A = gathered x^T [c][h], B = w[h][k].
//   D[m=quad*4+r][n=l15]: lane (l15,quad) holds wf[k=l15][c=nt*16+quad*4+r].
// wf LDS: element (k,p,c) at byte row*128 + (c*2 ^ (key(row)<<4)),
//   row = k*16+p, key(row) = ((row>>4)^row)&7.
//   Store: row=l15*16+p, key=(l15^p)&7.  Read: row=(s>>1)*16+l15,
//   key=((s>>1)^l15)&7, chunk=((s&1)*64+quad*16)^key<<4 (16B aligned).
__global__ __launch_bounds__(512, 4) void kpconv_fused(
    const float* __restrict__ q_pts, const float* __restrict__ s_pts,
    const int* __restrict__ inds, const unsigned short* __restrict__ xb,
    const float* __restrict__ kpts, const unsigned short* __restrict__ Wt,
    const float* __restrict__ bias, float* __restrict__ out)
{
    __shared__ float smem0[2112];                 // nb (512 float4 = 8192B) / outs (16x132 f32)
    __shared__ unsigned short wfs[15 * 16 * 64];  // 30720 B  (total 39168 B)

    const int tid  = threadIdx.x;
    const int wav  = tid >> 6;        // 0..7
    const int lane = tid & 63;
    const int l15  = lane & 15;
    const int quad = lane >> 4;
    const int p0   = blockIdx.x * PPB;

    // ---- stage 16 points x 32 neighbor displacements ----
    {
        float4* nb = (float4*)smem0;
        const int p = tid >> 5, h = tid & 31;
        const int n = p0 + p;
        int m = inds[n * HNB + h];
        float qx = q_pts[n * 3 + 0];
        float qy = q_pts[n * 3 + 1];
        float qz = q_pts[n * 3 + 2];
        nb[p * HNB + h] = make_float4(s_pts[m * 3 + 0] - qx,
                                      s_pts[m * 3 + 1] - qy,
                                      s_pts[m * 3 + 2] - qz,
                                      __int_as_float(m));
    }
    __syncthreads();

    // ---- Phase A: 2 points per wave, all 32 gathers in flight per point ----
    const bool kvalid = (l15 < KPTS);
    const int  kidx   = kvalid ? l15 : 0;
    const float kx = kpts[kidx * 3 + 0];
    const float ky = kpts[kidx * 3 + 1];
    const float kz = kpts[kidx * 3 + 2];

#pragma unroll
    for (int pp = 0; pp < 2; ++pp) {
        const int p = wav * 2 + pp;
        const float4* nb = (const float4*)smem0;

        bf16x8 af;
        const unsigned short* bj[8];
#pragma unroll
        for (int j = 0; j < 8; ++j) {
            float4 v = nb[p * HNB + quad * 8 + j];
            bj[j] = xb + (((size_t)__float_as_int(v.w)) << 6) + l15;
            float dx = v.x - kx, dy = v.y - ky, dz = v.z - kz;
            float d  = sqrtf(dx * dx + dy * dy + dz * dz);
            float w  = kvalid ? fmaxf(0.f, 1.f - d * INV_EXT) : 0.f;
            af[j] = (short)f2bf(w);
        }

        // issue all 32 gather loads (offset-immediate from 8 base pointers)
        unsigned int gv[32];
#pragma unroll
        for (int j = 0; j < 8; ++j)
#pragma unroll
            for (int nt = 0; nt < 4; ++nt)
                gv[j * 4 + nt] = bj[j][nt * 16];

        f32x4 acc[4];
#pragma unroll
        for (int nt = 0; nt < 4; ++nt) acc[nt] = (f32x4){0.f, 0.f, 0.f, 0.f};

#pragma unroll
        for (int nt = 0; nt < 4; ++nt) {
            union { unsigned int u[4]; bf16x8 f; } pk;
#pragma unroll
            for (int jj = 0; jj < 4; ++jj)
                pk.u[jj] = gv[(2 * jj) * 4 + nt] | (gv[(2 * jj + 1) * 4 + nt] << 16);
            acc[nt] = __builtin_amdgcn_mfma_f32_16x16x32_bf16(pk.f, af, acc[nt], 0, 0, 0);
        }

        if (kvalid) {   // lane's k = l15 (k==15 unused)
            char* rp = (char*)wfs + (l15 * 16 + p) * 128;
            const int key = ((l15 ^ p) & 7) << 4;
#pragma unroll
            for (int nt = 0; nt < 4; ++nt) {
                unsigned int lo = (unsigned)f2bf(acc[nt][0]) | ((unsigned)f2bf(acc[nt][1]) << 16);
                unsigned int hi = (unsigned)f2bf(acc[nt][2]) | ((unsigned)f2bf(acc[nt][3]) << 16);
                *(uint2*)(rp + ((nt * 32 + quad * 8) ^ key)) = make_uint2(lo, hi);
            }
        }
    }
    __syncthreads();

    // ---- Phase B: wave = 16-col group, full K (30 steps) ----
    f32x4 oacc = (f32x4){0.f, 0.f, 0.f, 0.f};
    const unsigned short* b0 = Wt + (size_t)(wav * 16 + l15) * KDIM + quad * 8;

#pragma unroll
    for (int s = 0; s < 30; ++s) {
        const int row = (s >> 1) * 16 + l15;
        const int key = (((s >> 1) ^ l15) & 7) << 4;
        bf16x8 afr = *(const bf16x8*)((const char*)wfs + row * 128 +
                                      (((s & 1) * 64 + quad * 16) ^ key));
        bf16x8 wfr = *(const bf16x8*)(b0 + s * 32);
        oacc = __builtin_amdgcn_mfma_f32_16x16x32_bf16(afr, wfr, oacc, 0, 0, 0);
    }

    // ---- epilogue: stage in LDS (reuse smem0), write full lines ----
    const float bv = bias[wav * 16 + l15];
    __syncthreads();                       // nb reads done; safe to reuse smem0
#pragma unroll
    for (int r = 0; r < 4; ++r)
        smem0[(quad * 4 + r) * 132 + wav * 16 + l15] = oacc[r] + bv;
    __syncthreads();
    {
        const int row = tid >> 5, c4 = (tid & 31) * 4;   // 16 rows x 32 float4
        float4 o4 = *(const float4*)&smem0[row * 132 + c4];
        *(float4*)&out[(size_t)(p0 + row) * COUTG + c4] = o4;
    }
}

extern "C" void kernel_launch(void* const* d_in, const int* in_sizes, int n_in,
                              void* d_out, int out_size, void* d_ws, size_t ws_size,
                              hipStream_t stream) {
    const float* q_pts = (const float*)d_in[0];
    const float* s_pts = (const float*)d_in[1];
    const int*   inds  = (const int*)d_in[2];
    const float* x     = (const float*)d_in[3];
    const float* kpts  = (const float*)d_in[4];
    const float* wgt   = (const float*)d_in[5];
    const float* bias  = (const float*)d_in[6];
    float* out = (float*)d_out;

    // ws layout: xb [50000*64] bf16 | Wt [128*960] bf16
    unsigned short* xb = (unsigned short*)d_ws;
    unsigned short* Wt = xb + (size_t)MSUP * CING;

    kpconv_prep<<<X2BF_BLKS + WT_BLKS, 256, 0, stream>>>(x, xb, wgt, Wt);
    kpconv_fused<<<NPTS / PPB, 512, 0, stream>>>(q_pts, s_pts, inds, xb, kpts, Wt, bias, out);
}

// Round 5
// 176.748 us; speedup vs baseline: 1.1709x; 1.1384x over previous
//
#include <hip/hip_runtime.h>

// KPConv pipeline v7 — back to SPLIT (fused structure was 40us worse than
// split and invariant under 3 fixes; ~75us of bench time is fixed overhead):
//   k_prep: x -> xb bf16  +  Wt transpose (full-line writes).  (~3us)
//   k_agg3: 1 point/wave, 8 pts/block (512 thr), grid 6250.
//           All 32 gathers in flight per point; swapped-operand MFMA ->
//           lane-contiguous c -> packed 8B wf stores (was 16 scalar 2B).
//   k_gemm3: 64x128 tile, BK=64, double-buffered LDS staged via
//           global_load_lds(16B) with source-side XOR swizzle (linear LDS
//           dest, swizzled global src, XOR on ds_read_b128 -> <=2-way).

#define NPTS   50000
#define NPAD   50048
#define HNB    32
#define KPTS   15
#define CING   64
#define COUTG  128
#define KDIM   960
#define MSUP   50000
#define INV_EXT 13.888889f

#define X2BF_BLKS 1563  // ceil(50000*64/8/256)
#define WT_BLKS   15    // 960/64
#define TWP       72    // u16 pitch in wt transpose tile

typedef __attribute__((ext_vector_type(8))) short bf16x8;
typedef __attribute__((ext_vector_type(8))) unsigned short u16x8;
typedef __attribute__((ext_vector_type(4))) float f32x4;

static __device__ __forceinline__ unsigned short f2bf(float f) {
    unsigned int u = __float_as_uint(f);
    u += 0x7FFFu + ((u >> 16) & 1u);
    return (unsigned short)(u >> 16);
}

static __device__ __forceinline__ void gload_lds16(const unsigned short* g,
                                                   unsigned short* l) {
    __builtin_amdgcn_global_load_lds(
        (const __attribute__((address_space(1))) void*)g,
        (__attribute__((address_space(3))) void*)l, 16, 0, 0);
}

// ---------------- k_prep: x->bf16 + weight transpose ----------------
__global__ __launch_bounds__(256) void kpconv_prep(const float* __restrict__ x,
                                                   unsigned short* __restrict__ xb,
                                                   const float* __restrict__ wgt,
                                                   unsigned short* __restrict__ Wt) {
    __shared__ unsigned short tw[128 * TWP];
    const int tid = threadIdx.x;
    if (blockIdx.x < X2BF_BLKS) {
        int i = (blockIdx.x * 256 + tid) * 8;
        if (i >= MSUP * CING) return;
        float4 a = *(const float4*)(x + i);
        float4 b = *(const float4*)(x + i + 4);
        u16x8 o;
        o[0] = f2bf(a.x); o[1] = f2bf(a.y); o[2] = f2bf(a.z); o[3] = f2bf(a.w);
        o[4] = f2bf(b.x); o[5] = f2bf(b.y); o[6] = f2bf(b.z); o[7] = f2bf(b.w);
        *(u16x8*)(xb + i) = o;
        return;
    }
    const int kc0 = (blockIdx.x - X2BF_BLKS) * 64;
#pragma unroll
    for (int it = 0; it < 32; ++it) {
        int idx = it * 256 + tid;          // kcl*128 + o
        int kcl = idx >> 7, o = idx & 127;
        tw[o * TWP + kcl] = f2bf(wgt[(size_t)(kc0 + kcl) * COUTG + o]);
    }
    __syncthreads();
#pragma unroll
    for (int it = 0; it < 4; ++it) {
        int idx = it * 256 + tid;          // o*8 + c16
        int o = idx >> 3, c16 = idx & 7;
        uint4 v = *(const uint4*)&tw[o * TWP + c16 * 8];
        *(uint4*)&Wt[(size_t)o * KDIM + kc0 + c16 * 8] = v;
    }
}

// ---------------- k_agg3: MFMA aggregate (split, packed stores) ----------------
// 1 wave = 1 point; 8 waves/block; grid 6250. Swapped operands:
//   A = gathered x: lane (l15,quad) elem j -> x[nb(h=quad*8+j)][nt*16+l15]
//   B = w:          lane l15 = k,   elem j -> w(h=quad*8+j, k)
//   D[m=quad*4+r][n=l15] = wf[k=l15][c = nt*16 + quad*4 + r]  (c lane-contig)
__global__ __launch_bounds__(512, 4) void kpconv_agg3(
    const float* __restrict__ q_pts, const float* __restrict__ s_pts,
    const int* __restrict__ inds, const unsigned short* __restrict__ xb,
    const float* __restrict__ kpts, unsigned short* __restrict__ wf)
{
    __shared__ float4 nb[8 * HNB];   // 4096 B

    const int tid  = threadIdx.x;
    const int wav  = tid >> 6;
    const int lane = tid & 63;
    const int l15  = lane & 15;
    const int quad = lane >> 4;
    const int n    = blockIdx.x * 8 + wav;

    if (lane < HNB) {
        int m = inds[n * HNB + lane];
        float qx = q_pts[n * 3 + 0];
        float qy = q_pts[n * 3 + 1];
        float qz = q_pts[n * 3 + 2];
        nb[wav * HNB + lane] = make_float4(s_pts[m * 3 + 0] - qx,
                                           s_pts[m * 3 + 1] - qy,
                                           s_pts[m * 3 + 2] - qz,
                                           __int_as_float(m));
    }
    __syncthreads();

    const bool kvalid = (l15 < KPTS);
    const int  kidx   = kvalid ? l15 : 0;
    const float kx = kpts[kidx * 3 + 0];
    const float ky = kpts[kidx * 3 + 1];
    const float kz = kpts[kidx * 3 + 2];

    bf16x8 af;
    const unsigned short* bj[8];
#pragma unroll
    for (int j = 0; j < 8; ++j) {
        float4 v = nb[wav * HNB + quad * 8 + j];
        bj[j] = xb + (((size_t)__float_as_int(v.w)) << 6) + l15;
        float dx = v.x - kx, dy = v.y - ky, dz = v.z - kz;
        float d  = sqrtf(dx * dx + dy * dy + dz * dz);
        float w  = kvalid ? fmaxf(0.f, 1.f - d * INV_EXT) : 0.f;
        af[j] = (short)f2bf(w);
    }

    // all 32 gather loads in flight (offset-immediate from 8 base pointers)
    unsigned int gv[32];
#pragma unroll
    for (int j = 0; j < 8; ++j)
#pragma unroll
        for (int nt = 0; nt < 4; ++nt)
            gv[j * 4 + nt] = bj[j][nt * 16];

    f32x4 acc[4];
#pragma unroll
    for (int nt = 0; nt < 4; ++nt) acc[nt] = (f32x4){0.f, 0.f, 0.f, 0.f};

#pragma unroll
    for (int nt = 0; nt < 4; ++nt) {
        union { unsigned int u[4]; bf16x8 f; } pk;
#pragma unroll
        for (int jj = 0; jj < 4; ++jj)
            pk.u[jj] = gv[(2 * jj) * 4 + nt] | (gv[(2 * jj + 1) * 4 + nt] << 16);
        acc[nt] = __builtin_amdgcn_mfma_f32_16x16x32_bf16(pk.f, af, acc[nt], 0, 0, 0);
    }

    if (kvalid) {   // lane's k = l15 (k==15 unused; KDIM = 15*64)
        unsigned short* wp = wf + (size_t)n * KDIM + l15 * CING + quad * 4;
#pragma unroll
        for (int nt = 0; nt < 4; ++nt) {
            unsigned int lo = (unsigned)f2bf(acc[nt][0]) | ((unsigned)f2bf(acc[nt][1]) << 16);
            unsigned int hi = (unsigned)f2bf(acc[nt][2]) | ((unsigned)f2bf(acc[nt][3]) << 16);
            *(uint2*)(wp + nt * 16) = make_uint2(lo, hi);
        }
    }
}

// ---------------- k_gemm3: 64x128 tile, BK=64, global_load_lds dbuf ----------------
#define GBM 64
#define GBK 64

__global__ __launch_bounds__(256) void kpconv_gemm3(
    const unsigned short* __restrict__ A,   // wf [NPAD][960]
    const unsigned short* __restrict__ Bt,  // Wt [128][960]
    const float* __restrict__ bias,
    float* __restrict__ out)
{
    __shared__ unsigned short As[2][GBM * GBK];     // 2 x 8 KB
    __shared__ unsigned short Bs[2][COUTG * GBK];   // 2 x 16 KB  (48 KB total)

    const int tid  = threadIdx.x;
    const int wave = tid >> 6;
    const int lane = tid & 63;
    const int l15  = lane & 15;
    const int quad = lane >> 4;
    const long blockM = (long)blockIdx.x * GBM;

    f32x4 acc[8];
#pragma unroll
    for (int i = 0; i < 8; ++i) acc[i] = (f32x4){0.f, 0.f, 0.f, 0.f};

    // source swizzle: lane -> local row = lane>>3, fetched chunk = (lane&7)^(lane>>3)
    const int rloc = lane >> 3;
    const int csw  = (lane & 7) ^ rloc;

    auto STAGE = [&](int buf, int t) {
        const int kb = t * GBK;
#pragma unroll
        for (int i = 0; i < 2; ++i) {   // A: wave stages rows wave*16 + i*8 ..+8
            const int rb = wave * 16 + i * 8;
            const unsigned short* g = A + (size_t)(blockM + rb + rloc) * KDIM + kb + csw * 8;
            gload_lds16(g, &As[buf][rb * GBK]);
        }
#pragma unroll
        for (int i = 0; i < 4; ++i) {   // B: wave stages rows wave*32 + i*8 ..+8
            const int rb = wave * 32 + i * 8;
            const unsigned short* g = Bt + (size_t)(rb + rloc) * KDIM + kb + csw * 8;
            gload_lds16(g, &Bs[buf][rb * GBK]);
        }
    };

    STAGE(0, 0);
    __syncthreads();    // compiler drains vmcnt before s_barrier

    for (int t = 0; t < 15; ++t) {
        const int cur = t & 1;
        if (t + 1 < 15) STAGE(cur ^ 1, t + 1);   // async prefetch overlaps MFMA
#pragma unroll
        for (int ch = 0; ch < 2; ++ch) {
            const int soff = (((ch * 4 + quad) ^ (l15 & 7)) * 8);   // XOR de-swizzle
            bf16x8 afr = *(const bf16x8*)&As[cur][(wave * 16 + l15) * GBK + soff];
#pragma unroll
            for (int nf = 0; nf < 8; ++nf) {
                bf16x8 bfr = *(const bf16x8*)&Bs[cur][(nf * 16 + l15) * GBK + soff];
                acc[nf] = __builtin_amdgcn_mfma_f32_16x16x32_bf16(afr, bfr, acc[nf], 0, 0, 0);
            }
        }
        __syncthreads();   // drains prefetch + frees cur buffer for t+2
    }

    const long r0 = blockM + wave * 16 + quad * 4;
#pragma unroll
    for (int nf = 0; nf < 8; ++nf) {
        const int col = nf * 16 + l15;
        const float bv = bias[col];
#pragma unroll
        for (int r = 0; r < 4; ++r) {
            long row = r0 + r;
            if (row < NPTS) out[row * COUTG + col] = acc[nf][r] + bv;
        }
    }
}

extern "C" void kernel_launch(void* const* d_in, const int* in_sizes, int n_in,
                              void* d_out, int out_size, void* d_ws, size_t ws_size,
                              hipStream_t stream) {
    const float* q_pts = (const float*)d_in[0];
    const float* s_pts = (const float*)d_in[1];
    const int*   inds  = (const int*)d_in[2];
    const float* x     = (const float*)d_in[3];
    const float* kpts  = (const float*)d_in[4];
    const float* wgt   = (const float*)d_in[5];
    const float* bias  = (const float*)d_in[6];
    float* out = (float*)d_out;

    // ws layout: wf [NPAD*960] bf16 | xb [50000*64] bf16 | Wt [128*960] bf16
    unsigned short* wfp = (unsigned short*)d_ws;
    unsigned short* xb  = wfp + (size_t)NPAD * KDIM;
    unsigned short* Wt  = xb + (size_t)MSUP * CING;

    kpconv_prep<<<X2BF_BLKS + WT_BLKS, 256, 0, stream>>>(x, xb, wgt, Wt);
    kpconv_agg3<<<NPTS / 8, 512, 0, stream>>>(q_pts, s_pts, inds, xb, kpts, wfp);
    kpconv_gemm3<<<NPAD / GBM, 256, 0, stream>>>(wfp, Wt, bias, out);
}